// Round 8
// baseline (173.712 us; speedup 1.0000x reference)
//
#include <hip/hip_runtime.h>
#include <hip/hip_bf16.h>

#define HID  128
#define NRAD 16
#define NT   100      // atom types (emb rows)

// LDS (dynamic):
//   Pl : f32 [NT][260] (260 dw stride -> 4-bank rotation/row)  104000 B
//   rb : [128 edges][256 B] swizzled bf16 r-tile                32768 B
#define PL_BYTES   (NT * 260 * 4)
#define RB_OFF     PL_BYTES
#define LDS_BYTES  (RB_OFF + 128 * 256)     // 136768 (<160K, 1 block/CU)

// Workspace: P f32 [NT][260] (104000) | W3 bf16 [128][128] (32768)
//          | Wr32 bf16 [128][32] (8192; col16 = b_rbf, cols 17..31 = 0)
#define WS_W3_OFF   PL_BYTES
#define WS_WR_OFF   (WS_W3_OFF + HID * HID * 2)

typedef __attribute__((ext_vector_type(4))) float f32x4;
typedef __attribute__((ext_vector_type(8))) __bf16 bf16x8;
typedef __attribute__((ext_vector_type(4))) __bf16 bf16x4;

union F8 { bf16x8 b; int4 i4; };
union B4 { bf16x4 b4; int2 i2; };

__device__ inline unsigned short f2bfbits(float f){
  unsigned int u = __float_as_uint(f);
  u += 0x7FFFu + ((u >> 16) & 1u);
  return (unsigned short)(u >> 16);
}

__device__ inline float silu_f(float v){
  return v * __builtin_amdgcn_rcpf(1.0f + __expf(-v));
}

// ---------------------------------------------------------------------------
// Setup (one launch):
//   blocks [0, ntypes)        : P[t][0:128]=emb@W1^T+b_lin ; [128:256]=emb@W2^T
//   blocks [ntypes, +64)      : W3 bf16 conversion (128x128)
//   blocks [ntypes+64, +16)   : Wr32 bf16 [128][32]: cols0-15=W_rbf, col16=b_rbf
// ---------------------------------------------------------------------------
__global__ void setup_kernel(const float* __restrict__ emb,
                             const float* __restrict__ W_lin,
                             const float* __restrict__ b_lin,
                             const float* __restrict__ W_rbf,
                             const float* __restrict__ b_rbf,
                             int ntypes,
                             float* __restrict__ P,
                             unsigned short* __restrict__ W3,
                             unsigned short* __restrict__ Wr32){
  int blk = blockIdx.x;
  int n = threadIdx.x;                // 0..255
  if (blk < ntypes){
    __shared__ float er[HID];
    if (n < HID) er[n] = emb[blk * HID + n];
    __syncthreads();
    int half = n >> 7, nn = n & 127;
    const float4* w4 = (const float4*)(W_lin + (size_t)nn * (3 * HID) + half * HID);
    float s = half ? 0.0f : b_lin[nn];
    #pragma unroll 8
    for (int k4 = 0; k4 < HID / 4; ++k4){
      float4 w = w4[k4];
      s += er[k4*4+0]*w.x + er[k4*4+1]*w.y + er[k4*4+2]*w.z + er[k4*4+3]*w.w;
    }
    P[blk * 260 + n] = s;
    if (n < 4) P[blk * 260 + 256 + n] = 0.f;   // deterministic pad
  } else if (blk < ntypes + 64){
    int idx = (blk - ntypes) * 256 + n;        // 0..16383
    int r = idx >> 7, k = idx & 127;
    W3[idx] = f2bfbits(W_lin[(size_t)r * (3 * HID) + 2 * HID + k]);
  } else {
    int idx = (blk - ntypes - 64) * 256 + n;   // 0..4095
    int r = idx >> 5, k = idx & 31;
    float v = (k < 16) ? W_rbf[r * NRAD + k] : (k == 16 ? b_rbf[r] : 0.f);
    Wr32[idx] = f2bfbits(v);
  }
}

// ---------------------------------------------------------------------------
// Edge kernel: 512 threads (8 waves), 128 edges/tile, grid-stride.
// FULLY WAVE-LOCAL: wave wv owns edges [wv*16, wv*16+16) of each tile for
// BOTH phases -> zero per-tile barriers; waves free-run their own pipelines.
//   phase 1: r = silu(rbf @ Wrbf^T + b) (bias via augmented k=16 column)
//            -> bf16, XOR-swizzled per-wave LDS rows
//   phase 2: acc = W3 * r^T  with the FULL W3 held in registers
//            (32 int4 frags = 128 VGPR/lane, loaded once)
//   epilogue: out = silu(acc + P1[x[i]] + P2[x[j]]), P f32 in LDS
// Per-lane 2-deep ei/ej->x index pipeline; rbf prefetched 1 tile ahead.
// ---------------------------------------------------------------------------
__global__ __launch_bounds__(512, 2) void edge_kernel(
    const float* __restrict__ rbf,
    const int*   __restrict__ ei,
    const int*   __restrict__ ej,
    const int*   __restrict__ x,
    const unsigned short* __restrict__ Wr32,  // bf16 [128][32]
    const float* __restrict__ Pg,             // f32 [NT][260]
    const unsigned short* __restrict__ W3,    // bf16 [128][128]
    float* __restrict__ out,
    int E, int ntile)
{
  extern __shared__ char smem[];
  float* Pl = (float*)smem;
  char*  rb = smem + RB_OFF;

  const int tid  = threadIdx.x;
  const int lane = tid & 63;
  const int wv   = tid >> 6;        // 0..7
  const int erow = lane & 15;
  const int kgrp = lane >> 4;       // 0..3
  const int e_l  = wv * 16 + erow;  // the ONE edge-slot this lane owns
  const int G    = gridDim.x;

  // ---- stage P into LDS ---------------------------------------------------
  for (int i = tid; i < PL_BYTES / 16; i += 512)
    ((int4*)smem)[i] = ((const int4*)Pg)[i];

  // ---- persistent register fragments --------------------------------------
  F8 wr[8];                                    // Wrbf+bias rows (phase1 A)
  #pragma unroll
  for (int t = 0; t < 8; ++t)
    wr[t].i4 = *(const int4*)(Wr32 + (t * 16 + erow) * 32 + kgrp * 8);

  F8 w3r[32];                                  // FULL W3 (phase2 A), 128 VGPR
  #pragma unroll
  for (int t = 0; t < 8; ++t)
    #pragma unroll
    for (int s = 0; s < 4; ++s)
      w3r[t * 4 + s].i4 = *(const int4*)(W3 + (t * 16 + erow) * HID + s * 32 + kgrp * 8);

  // ---- prologue: tile 0 of this block's stream ----------------------------
  int tile = blockIdx.x;
  long g0 = (long)tile * 128 + e_l; if (g0 > (long)E - 1) g0 = E - 1;
  int xa = x[ei[g0]];
  int xb = x[ej[g0]];
  f32x4 f0 = {0,0,0,0}, f1 = {0,0,0,0};
  if (kgrp < 2){
    const f32x4* s4 = (const f32x4*)(rbf + g0 * NRAD + kgrp * 8);
    f0 = __builtin_nontemporal_load(s4);
    f1 = __builtin_nontemporal_load(s4 + 1);
  }

  __syncthreads();                             // P staged (only barrier)

  while (tile < ntile){
    const long base = (long)tile * 128;
    const long ge   = base + e_l;
    const int  next = tile + G;

    // ---- issue next tile's index loads (latency hidden under phase 1) ----
    long gn = (long)next * 128 + e_l; if (gn > (long)E - 1) gn = E - 1;
    int nai = ei[gn];
    int naj = ej[gn];
    f32x4 nf0 = {0,0,0,0}, nf1 = {0,0,0,0};
    if (kgrp < 2){
      const f32x4* s4 = (const f32x4*)(rbf + gn * NRAD + kgrp * 8);
      nf0 = __builtin_nontemporal_load(s4);
      nf1 = __builtin_nontemporal_load(s4 + 1);
    }

    // ---- phase 1: r for own 16 edges -> swizzled LDS ----------------------
    F8 fb; fb.i4 = make_int4(0, 0, 0, 0);
    if (kgrp < 2){
      fb.b[0]=(__bf16)f0.x; fb.b[1]=(__bf16)f0.y; fb.b[2]=(__bf16)f0.z; fb.b[3]=(__bf16)f0.w;
      fb.b[4]=(__bf16)f1.x; fb.b[5]=(__bf16)f1.y; fb.b[6]=(__bf16)f1.z; fb.b[7]=(__bf16)f1.w;
    } else if (kgrp == 2){
      fb.b[0] = (__bf16)1.0f;                  // bias column (k=16)
    }
    #pragma unroll
    for (int t = 0; t < 8; ++t){
      f32x4 acc = {0.f, 0.f, 0.f, 0.f};
      acc = __builtin_amdgcn_mfma_f32_16x16x32_bf16(wr[t].b, fb.b, acc, 0, 0, 0);
      B4 pk;                                   // D: col=edge e_l, row=kgrp*4+r
      pk.b4[0] = (__bf16)silu_f(acc[0]);
      pk.b4[1] = (__bf16)silu_f(acc[1]);
      pk.b4[2] = (__bf16)silu_f(acc[2]);
      pk.b4[3] = (__bf16)silu_f(acc[3]);
      int byte = (e_l << 8) + t * 32 + kgrp * 8;
      byte ^= (e_l & 7) << 4;
      *(int2*)(rb + byte) = pk.i2;
    }

    // ---- next tile's x-gathers (ei loads have returned by now) ------------
    int nxa = x[nai];
    int nxb = x[naj];

    // wave-local LDS RAW: DS ops are in-order per wave; wait for read data
    asm volatile("s_waitcnt lgkmcnt(0)" ::: "memory");

    // ---- phase 2: acc = W3 * r^T (W3 from registers) ----------------------
    f32x4 acc2[8];
    #pragma unroll
    for (int t = 0; t < 8; ++t) acc2[t] = (f32x4){0.f, 0.f, 0.f, 0.f};

    #pragma unroll
    for (int s = 0; s < 4; ++s){
      int byte = (e_l << 8) + s * 64 + kgrp * 16;
      byte ^= (e_l & 7) << 4;
      F8 bB; bB.i4 = *(const int4*)(rb + byte);   // B: col=edge e_l
      #pragma unroll
      for (int t = 0; t < 8; ++t)
        acc2[t] = __builtin_amdgcn_mfma_f32_16x16x32_bf16(w3r[t*4+s].b, bB.b, acc2[t], 0, 0, 0);
    }

    // ---- epilogue: lane owns edge ge, n = t*16 + kgrp*4 + (0..3) ----------
    const float* pa = Pl + xa * 260;
    const float* pb = Pl + xb * 260 + 128;
    #pragma unroll
    for (int t = 0; t < 8; ++t){
      int nb = t * 16 + kgrp * 4;
      f32x4 p1 = *(const f32x4*)(pa + nb);
      f32x4 p2 = *(const f32x4*)(pb + nb);
      f32x4 o;
      o.x = silu_f(acc2[t][0] + p1.x + p2.x);
      o.y = silu_f(acc2[t][1] + p1.y + p2.y);
      o.z = silu_f(acc2[t][2] + p1.z + p2.z);
      o.w = silu_f(acc2[t][3] + p1.w + p2.w);
      if (ge < E)
        *(f32x4*)(out + ge * HID + nb) = o;
    }

    // ---- rotate pipeline ---------------------------------------------------
    f0 = nf0; f1 = nf1; xa = nxa; xb = nxb;
    tile = next;
  }
}

// ---------------------------------------------------------------------------
extern "C" void kernel_launch(void* const* d_in, const int* in_sizes, int n_in,
                              void* d_out, int out_size, void* d_ws, size_t ws_size,
                              hipStream_t stream){
  const int*   x    = (const int*)  d_in[0];
  const float* rbf  = (const float*)d_in[1];
  const int*   ei   = (const int*)  d_in[2];
  const int*   ej   = (const int*)  d_in[3];
  const float* emb  = (const float*)d_in[4];
  const float* Wrbf = (const float*)d_in[5];
  const float* brbf = (const float*)d_in[6];
  const float* Wlin = (const float*)d_in[7];
  const float* blin = (const float*)d_in[8];
  float* out = (float*)d_out;

  const int E      = in_sizes[2];
  const int ntypes = in_sizes[4] / HID;   // 100

  float*          P    = (float*)d_ws;
  unsigned short* W3   = (unsigned short*)((char*)d_ws + WS_W3_OFF);
  unsigned short* Wr32 = (unsigned short*)((char*)d_ws + WS_WR_OFF);

  setup_kernel<<<ntypes + 64 + 16, 256, 0, stream>>>(
      emb, Wlin, blin, Wrbf, brbf, ntypes, P, W3, Wr32);

  (void)hipFuncSetAttribute(reinterpret_cast<const void*>(&edge_kernel),
                            hipFuncAttributeMaxDynamicSharedMemorySize, LDS_BYTES);

  const int ntile = (E + 127) / 128;
  const int nblk  = ntile < 256 ? ntile : 256;
  edge_kernel<<<nblk, 512, LDS_BYTES, stream>>>(
      rbf, ei, ej, x, Wr32, P, W3, out, E, ntile);
}